// Round 12
// baseline (813.367 us; speedup 1.0000x reference)
//
#include <hip/hip_runtime.h>
#include <cstdint>

typedef __attribute__((ext_vector_type(8))) short short8;
typedef __attribute__((ext_vector_type(4))) float f32x4;
typedef __attribute__((ext_vector_type(2))) unsigned u32x2;
typedef unsigned short ushort_t;

constexpr int Bc = 4, Sc = 2048, Dc = 2048, Hc = 16, DKc = 128;
constexpr long NTOK = (long)Bc * Sc;          // 8192 rows
constexpr long OUT_ELEMS = NTOK * (long)Dc;   // 16777216
constexpr float SCALE = 0.08838834764831843f; // 1/sqrt(128)

__device__ __forceinline__ ushort_t f2bf(float f) {
  unsigned u = __builtin_bit_cast(unsigned, f);
  u = (u + 0x7FFFu + ((u >> 16) & 1u)) >> 16;
  return (ushort_t)u;
}

__device__ __forceinline__ short8 pack8(const f32x4& a, const f32x4& b) {
  short8 h;
  h[0] = (short)f2bf(a[0]); h[1] = (short)f2bf(a[1]);
  h[2] = (short)f2bf(a[2]); h[3] = (short)f2bf(a[3]);
  h[4] = (short)f2bf(b[0]); h[5] = (short)f2bf(b[1]);
  h[6] = (short)f2bf(b[2]); h[7] = (short)f2bf(b[3]);
  return h;
}

// async global->LDS, 16B per lane; lds dest is wave-uniform base + lane*16
__device__ __forceinline__ void gl2lds16(const ushort_t* g, ushort_t* l) {
  __builtin_amdgcn_global_load_lds(
      (__attribute__((address_space(1))) unsigned int*)(g),
      (__attribute__((address_space(3))) unsigned int*)(l), 16, 0, 0);
}

__device__ __forceinline__ void bar() {
  asm volatile("" ::: "memory");
  __builtin_amdgcn_s_barrier();
  asm volatile("" ::: "memory");
}

// ---------------------------------------------------------------------------
// Fused 3-projection GEMM, fp32 A source. C = A(8192x2048 fp32)*W(2048x2048)^T.
// 256x256 tile, BK=64, 512 thr (8 waves 2Mx4N), dbuf 128KB LDS.
// z=0: Q proj, z=1: K proj, z=2: V proj -> VT transposed.
// ---------------------------------------------------------------------------
__global__ __launch_bounds__(512, 2)
void proj_gemm(const float* __restrict__ qf, const float* __restrict__ kf,
               const float* __restrict__ vf,
               const ushort_t* __restrict__ Wqb, const ushort_t* __restrict__ Wkb,
               const ushort_t* __restrict__ Wvb,
               ushort_t* __restrict__ Qb, ushort_t* __restrict__ Kb,
               ushort_t* __restrict__ VTo)
{
  __shared__ __align__(16) ushort_t SM[2][2][2][128 * 64]; // [A/B][buf][half]

  const int z = blockIdx.z;
  const float* Afull = (z == 0) ? qf : (z == 1) ? kf : vf;
  const ushort_t* Bp = (z == 0) ? Wqb : (z == 1) ? Wkb : Wvb;
  ushort_t* Cp = (z == 0) ? Qb : (z == 1) ? Kb : VTo;

  const int tid = threadIdx.x, lane = tid & 63, wave = tid >> 6;
  const int wm = wave >> 2, wn = wave & 3;

  const int lin = blockIdx.y * 8 + blockIdx.x;
  const int swz = (lin & 7) * 32 + (lin >> 3);
  const long n0 = (long)(swz & 7) * 256;
  const long m0 = (long)(swz >> 3) * 256;

  constexpr int NT = 32;

  const float*    Ag = Afull + m0 * (long)Dc;
  const ushort_t* Bg = Bp + n0 * (long)Dc;

  auto stageB = [&](ushort_t* dst, int kt, int ht) {
#pragma unroll
    for (int c = 0; c < 2; ++c) {
      int U = (c * 8 + wave) * 64 + lane;
      int row = U >> 3, p = U & 7, u = p ^ (row & 7);
      gl2lds16(Bg + (long)(ht * 128 + row) * Dc + kt * 64 + u * 8,
               dst + (c * 8 + wave) * 512);
    }
  };
  auto loadA = [&](int kt, f32x4 alo[2][2], f32x4 ahi[2][2]) {
#pragma unroll
    for (int ht = 0; ht < 2; ++ht)
#pragma unroll
      for (int c = 0; c < 2; ++c) {
        int U = (c * 8 + wave) * 64 + lane;
        int row = U >> 3, p = U & 7, u = p ^ (row & 7);
        const float* g = Ag + (long)(ht * 128 + row) * Dc + kt * 64 + u * 8;
        alo[ht][c] = *(const f32x4*)g;
        ahi[ht][c] = *(const f32x4*)(g + 4);
      }
  };
  auto writeA = [&](int buf, const f32x4 alo[2][2], const f32x4 ahi[2][2]) {
#pragma unroll
    for (int ht = 0; ht < 2; ++ht)
#pragma unroll
      for (int c = 0; c < 2; ++c) {
        int chunk = c * 8 + wave;
        *(short8*)(&SM[0][buf][ht][chunk * 512 + lane * 8]) =
            pack8(alo[ht][c], ahi[ht][c]);
      }
  };

  stageB(&SM[1][0][0][0], 0, 0);
  stageB(&SM[1][0][1][0], 0, 1);
  stageB(&SM[1][1][0][0], 1, 0);
  {
    f32x4 alo[2][2], ahi[2][2];
    loadA(0, alo, ahi);
    asm volatile("s_waitcnt vmcnt(0)" ::: "memory");
    writeA(0, alo, ahi);
    asm volatile("s_waitcnt lgkmcnt(0)" ::: "memory");
  }
  __builtin_amdgcn_s_barrier();
  asm volatile("" ::: "memory");

  f32x4 acc[8][4] = {};

  for (int kt = 0; kt < NT; ++kt) {
    const int cur = kt & 1;
    const ushort_t* Acur = &SM[0][cur][0][0];
    const ushort_t* Bcur = &SM[1][cur][0][0];
    const int k1 = (kt + 1) & (NT - 1);
    const int k2 = (kt + 2) & (NT - 1);
    short8 af[4][2], bq0[2][2], bq1[2][2];
    f32x4 alo[2][2], ahi[2][2];

    // P0
#pragma unroll
    for (int mf = 0; mf < 4; ++mf)
#pragma unroll
      for (int ks = 0; ks < 2; ++ks) {
        int r = mf * 16 + (lane & 15);
        int u = ks * 4 + (lane >> 4), p = u ^ (r & 7);
        af[mf][ks] = *(const short8*)(Acur + wm * (128 * 64) + r * 64 + p * 8);
      }
#pragma unroll
    for (int nf = 0; nf < 2; ++nf)
#pragma unroll
      for (int ks = 0; ks < 2; ++ks) {
        int r = (wn & 1) * 64 + nf * 16 + (lane & 15);
        int u = ks * 4 + (lane >> 4), p = u ^ (r & 7);
        bq0[nf][ks] = *(const short8*)(Bcur + (wn >> 1) * (128 * 64) + r * 64 + p * 8);
      }
    stageB(&SM[1][cur ^ 1][1][0], k1, 1);
    bar();
    __builtin_amdgcn_s_setprio(1);
#pragma unroll
    for (int mf = 0; mf < 4; ++mf)
#pragma unroll
      for (int nf = 0; nf < 2; ++nf)
#pragma unroll
        for (int ks = 0; ks < 2; ++ks)
          acc[mf][nf] = __builtin_amdgcn_mfma_f32_16x16x32_bf16(af[mf][ks], bq0[nf][ks], acc[mf][nf], 0, 0, 0);
    __builtin_amdgcn_s_setprio(0);
    bar();

    // P1
#pragma unroll
    for (int nf = 0; nf < 2; ++nf)
#pragma unroll
      for (int ks = 0; ks < 2; ++ks) {
        int r = (wn & 1) * 64 + 32 + nf * 16 + (lane & 15);
        int u = ks * 4 + (lane >> 4), p = u ^ (r & 7);
        bq1[nf][ks] = *(const short8*)(Bcur + (wn >> 1) * (128 * 64) + r * 64 + p * 8);
      }
    loadA(k1, alo, ahi);
    bar();
    __builtin_amdgcn_s_setprio(1);
#pragma unroll
    for (int mf = 0; mf < 4; ++mf)
#pragma unroll
      for (int nf = 0; nf < 2; ++nf)
#pragma unroll
        for (int ks = 0; ks < 2; ++ks)
          acc[mf][2 + nf] = __builtin_amdgcn_mfma_f32_16x16x32_bf16(af[mf][ks], bq1[nf][ks], acc[mf][2 + nf], 0, 0, 0);
    __builtin_amdgcn_s_setprio(0);
    bar();

    // P2
#pragma unroll
    for (int mf = 0; mf < 4; ++mf)
#pragma unroll
      for (int ks = 0; ks < 2; ++ks) {
        int r = 64 + mf * 16 + (lane & 15);
        int u = ks * 4 + (lane >> 4), p = u ^ (r & 7);
        af[mf][ks] = *(const short8*)(Acur + wm * (128 * 64) + r * 64 + p * 8);
      }
    stageB(&SM[1][cur][0][0], k2, 0);
    bar();
    __builtin_amdgcn_s_setprio(1);
#pragma unroll
    for (int mf = 0; mf < 4; ++mf)
#pragma unroll
      for (int nf = 0; nf < 2; ++nf)
#pragma unroll
        for (int ks = 0; ks < 2; ++ks)
          acc[4 + mf][nf] = __builtin_amdgcn_mfma_f32_16x16x32_bf16(af[mf][ks], bq0[nf][ks], acc[4 + mf][nf], 0, 0, 0);
    __builtin_amdgcn_s_setprio(0);
    bar();

    // P3
    asm volatile("s_waitcnt vmcnt(2)" ::: "memory");
    writeA(cur ^ 1, alo, ahi);
    asm volatile("s_waitcnt lgkmcnt(0)" ::: "memory");
    bar();
    __builtin_amdgcn_s_setprio(1);
#pragma unroll
    for (int mf = 0; mf < 4; ++mf)
#pragma unroll
      for (int nf = 0; nf < 2; ++nf)
#pragma unroll
        for (int ks = 0; ks < 2; ++ks)
          acc[4 + mf][2 + nf] = __builtin_amdgcn_mfma_f32_16x16x32_bf16(af[mf][ks], bq1[nf][ks], acc[4 + mf][2 + nf], 0, 0, 0);
    __builtin_amdgcn_s_setprio(0);
    bar();
  }

  asm volatile("s_waitcnt vmcnt(0)" ::: "memory");

  if (z == 2) {
    bar();
    char* Tb = (char*)&SM[0][0][0][0];    // 256 rows(cg) x 512B(rg), XOR-swz
#pragma unroll
    for (int mq = 0; mq < 8; ++mq) {
#pragma unroll
      for (int nq = 0; nq < 4; ++nq) {
        int rg = wm * 128 + (mq >> 2) * 64 + (mq & 3) * 16 + ((lane >> 4) * 4);
        int cg = wn * 64 + (nq >> 1) * 32 + (nq & 1) * 16 + (lane & 15);
        u32x2 t;
        t[0] = (unsigned)f2bf(acc[mq][nq][0]) | ((unsigned)f2bf(acc[mq][nq][1]) << 16);
        t[1] = (unsigned)f2bf(acc[mq][nq][2]) | ((unsigned)f2bf(acc[mq][nq][3]) << 16);
        int off = cg * 512 + (((rg >> 3) ^ (cg & 31)) * 16) + (rg & 7) * 2;
        *(u32x2*)(Tb + off) = t;
      }
    }
    bar();
    const long bq = m0 >> 11;
    const long s0 = m0 & 2047;
#pragma unroll
    for (int i = 0; i < 16; ++i) {
      int row = i * 16 + (tid >> 5);
      int un  = tid & 31;
      int p = un ^ (row & 31);
      short8 val = *(const short8*)(Tb + row * 512 + p * 16);
      long cgg = n0 + row;
      long vtrow = ((cgg >> 7) * 4 + bq) * 128 + (cgg & 127);
      *(short8*)(&Cp[vtrow * (long)Sc + s0 + un * 8]) = val;
    }
  } else {
#pragma unroll
    for (int mq = 0; mq < 8; ++mq) {
#pragma unroll
      for (int nq = 0; nq < 4; ++nq) {
#pragma unroll
        for (int j = 0; j < 4; ++j) {
          long rg = m0 + wm * 128 + (mq >> 2) * 64 + (mq & 3) * 16 + ((lane >> 4) * 4) + j;
          long cg = n0 + wn * 64 + (nq >> 1) * 32 + (nq & 1) * 16 + (lane & 15);
          Cp[rg * (long)Dc + cg] = f2bf(acc[mq][nq][j]);
        }
      }
    }
  }
}

// ---------------------------------------------------------------------------
// Output-projection GEMM (bf16 A via gl2lds), 256x256 8-phase, fp32 C+residual.
// ---------------------------------------------------------------------------
__global__ __launch_bounds__(512, 2)
void out_gemm(const ushort_t* __restrict__ Ap, const ushort_t* __restrict__ Bp,
              float* __restrict__ Cp, const float* __restrict__ residual)
{
  __shared__ __align__(16) ushort_t SM[2][2][2][128 * 64];

  const int tid = threadIdx.x, lane = tid & 63, wave = tid >> 6;
  const int wm = wave >> 2, wn = wave & 3;
  const int lin = blockIdx.y * 8 + blockIdx.x;
  const int swz = (lin & 7) * 32 + (lin >> 3);
  const long n0 = (long)(swz & 7) * 256;
  const long m0 = (long)(swz >> 3) * 256;
  constexpr int NT = 32;

  const ushort_t* Ag = Ap + m0 * (long)Dc;
  const ushort_t* Bg = Bp + n0 * (long)Dc;

  auto stage = [&](const ushort_t* gb, ushort_t* dst, int kt, int ht) {
#pragma unroll
    for (int c = 0; c < 2; ++c) {
      int U = (c * 8 + wave) * 64 + lane;
      int row = U >> 3, p = U & 7, u = p ^ (row & 7);
      gl2lds16(gb + (long)(ht * 128 + row) * Dc + kt * 64 + u * 8,
               dst + (c * 8 + wave) * 512);
    }
  };

  stage(Bg, &SM[1][0][0][0], 0, 0);
  stage(Ag, &SM[0][0][0][0], 0, 0);
  stage(Bg, &SM[1][0][1][0], 0, 1);
  stage(Ag, &SM[0][0][1][0], 0, 1);
  stage(Bg, &SM[1][1][0][0], 1, 0);
  stage(Ag, &SM[0][1][0][0], 1, 0);
  asm volatile("s_waitcnt vmcnt(4)" ::: "memory");
  __builtin_amdgcn_s_barrier();
  asm volatile("" ::: "memory");

  f32x4 acc[8][4] = {};

  for (int kt = 0; kt < NT; ++kt) {
    const int cur = kt & 1;
    const ushort_t* Acur = &SM[0][cur][0][0];
    const ushort_t* Bcur = &SM[1][cur][0][0];
    const int k1 = (kt + 1) & (NT - 1);
    const int k2 = (kt + 2) & (NT - 1);
    short8 af[4][2], bq0[2][2], bq1[2][2];

#pragma unroll
    for (int mf = 0; mf < 4; ++mf)
#pragma unroll
      for (int ks = 0; ks < 2; ++ks) {
        int r = mf * 16 + (lane & 15);
        int u = ks * 4 + (lane >> 4), p = u ^ (r & 7);
        af[mf][ks] = *(const short8*)(Acur + wm * (128 * 64) + r * 64 + p * 8);
      }
#pragma unroll
    for (int nf = 0; nf < 2; ++nf)
#pragma unroll
      for (int ks = 0; ks < 2; ++ks) {
        int r = (wn & 1) * 64 + nf * 16 + (lane & 15);
        int u = ks * 4 + (lane >> 4), p = u ^ (r & 7);
        bq0[nf][ks] = *(const short8*)(Bcur + (wn >> 1) * (128 * 64) + r * 64 + p * 8);
      }
    stage(Bg, &SM[1][cur ^ 1][1][0], k1, 1);
    bar();
    __builtin_amdgcn_s_setprio(1);
#pragma unroll
    for (int mf = 0; mf < 4; ++mf)
#pragma unroll
      for (int nf = 0; nf < 2; ++nf)
#pragma unroll
        for (int ks = 0; ks < 2; ++ks)
          acc[mf][nf] = __builtin_amdgcn_mfma_f32_16x16x32_bf16(af[mf][ks], bq0[nf][ks], acc[mf][nf], 0, 0, 0);
    __builtin_amdgcn_s_setprio(0);
    bar();

#pragma unroll
    for (int nf = 0; nf < 2; ++nf)
#pragma unroll
      for (int ks = 0; ks < 2; ++ks) {
        int r = (wn & 1) * 64 + 32 + nf * 16 + (lane & 15);
        int u = ks * 4 + (lane >> 4), p = u ^ (r & 7);
        bq1[nf][ks] = *(const short8*)(Bcur + (wn >> 1) * (128 * 64) + r * 64 + p * 8);
      }
    stage(Ag, &SM[0][cur ^ 1][1][0], k1, 1);
    bar();
    __builtin_amdgcn_s_setprio(1);
#pragma unroll
    for (int mf = 0; mf < 4; ++mf)
#pragma unroll
      for (int nf = 0; nf < 2; ++nf)
#pragma unroll
        for (int ks = 0; ks < 2; ++ks)
          acc[mf][2 + nf] = __builtin_amdgcn_mfma_f32_16x16x32_bf16(af[mf][ks], bq1[nf][ks], acc[mf][2 + nf], 0, 0, 0);
    __builtin_amdgcn_s_setprio(0);
    bar();

#pragma unroll
    for (int mf = 0; mf < 4; ++mf)
#pragma unroll
      for (int ks = 0; ks < 2; ++ks) {
        int r = 64 + mf * 16 + (lane & 15);
        int u = ks * 4 + (lane >> 4), p = u ^ (r & 7);
        af[mf][ks] = *(const short8*)(Acur + wm * (128 * 64) + r * 64 + p * 8);
      }
    stage(Bg, &SM[1][cur][0][0], k2, 0);
    bar();
    __builtin_amdgcn_s_setprio(1);
#pragma unroll
    for (int mf = 0; mf < 4; ++mf)
#pragma unroll
      for (int nf = 0; nf < 2; ++nf)
#pragma unroll
        for (int ks = 0; ks < 2; ++ks)
          acc[4 + mf][nf] = __builtin_amdgcn_mfma_f32_16x16x32_bf16(af[mf][ks], bq0[nf][ks], acc[4 + mf][nf], 0, 0, 0);
    __builtin_amdgcn_s_setprio(0);
    bar();

    stage(Ag, &SM[0][cur][0][0], k2, 0);
    asm volatile("s_waitcnt vmcnt(4)" ::: "memory");
    bar();
    __builtin_amdgcn_s_setprio(1);
#pragma unroll
    for (int mf = 0; mf < 4; ++mf)
#pragma unroll
      for (int nf = 0; nf < 2; ++nf)
#pragma unroll
        for (int ks = 0; ks < 2; ++ks)
          acc[4 + mf][2 + nf] = __builtin_amdgcn_mfma_f32_16x16x32_bf16(af[mf][ks], bq1[nf][ks], acc[4 + mf][2 + nf], 0, 0, 0);
    __builtin_amdgcn_s_setprio(0);
    bar();
  }

  asm volatile("s_waitcnt vmcnt(0)" ::: "memory");

#pragma unroll
  for (int mq = 0; mq < 8; ++mq) {
#pragma unroll
    for (int nq = 0; nq < 4; ++nq) {
#pragma unroll
      for (int j = 0; j < 4; ++j) {
        long rg = m0 + wm * 128 + (mq >> 2) * 64 + (mq & 3) * 16 + ((lane >> 4) * 4) + j;
        long cg = n0 + wn * 64 + (nq >> 1) * 32 + (nq & 1) * 16 + (lane & 15);
        Cp[rg * (long)Dc + cg] = acc[mq][nq][j] + residual[rg * (long)Dc + cg];
      }
    }
  }
}

// ---------------------------------------------------------------------------
// Flash attention: exact R6 structure (best known) + T5 setprio around MFMA.
// K/V reg-staged, t+1 loads issued BEFORE the 2nd __syncthreads; nt P stores.
// LDS: Qs 32K + Ks 16K + Vs 16K + Ps 16K = 80KB -> 2 blocks/CU.
// ---------------------------------------------------------------------------
__global__ __launch_bounds__(256, 2)
void flash_attn(const ushort_t* __restrict__ Qb, const ushort_t* __restrict__ Kb,
                const ushort_t* __restrict__ VT, float* __restrict__ attn,
                ushort_t* __restrict__ Cb)
{
  __shared__ __align__(16) ushort_t Qs[128 * 128]; // swz u^(row&15)
  __shared__ __align__(16) ushort_t Ks[64 * 128];  // swz u^(row&15)
  __shared__ __align__(16) ushort_t Vs[128 * 64];  // swz u^(row&7)
  __shared__ __align__(16) ushort_t Ps[128 * 64];  // swz u^(row&7)

  const int tid = threadIdx.x, lane = tid & 63, wave = tid >> 6;
  const int wr = wave >> 1, wc = wave & 1;

  const int bid = blockIdx.x;
  const int xcd = bid & 7, slot = bid >> 3;
  const int n = xcd * 8 + (slot >> 4);
  const long m0 = (long)(slot & 15) * 128;
  const int b = n & 3, h = n >> 2;

  const ushort_t* Qg = Qb + ((long)b * Sc) * Dc + (long)h * DKc;
  const ushort_t* Kg = Kb + ((long)b * Sc) * Dc + (long)h * DKc;
  const ushort_t* Vg = VT + (long)n * DKc * (long)Sc;
  float* Pg = attn + (long)n * Sc * (long)Sc;

#pragma unroll
  for (int c8 = 0; c8 < 8; ++c8) {
    int chunk = c8 * 4 + wave;
    int U = chunk * 64 + lane;
    int row = U >> 4, p = U & 15, u = p ^ (row & 15);
    gl2lds16(Qg + (m0 + row) * (long)Dc + u * 8, &Qs[chunk * 512]);
  }

  auto kaddr = [&](int t, int c4) -> const short8* {
    int chunk = c4 * 4 + wave;
    int U = chunk * 64 + lane;
    int row = U >> 4, p = U & 15, u = p ^ (row & 15);
    return (const short8*)(Kg + ((long)t * 64 + row) * (long)Dc + u * 8);
  };
  auto vaddr = [&](int t, int c4) -> const short8* {
    int chunk = c4 * 4 + wave;
    int U = chunk * 64 + lane;
    int row = U >> 3, p = U & 7, u = p ^ (row & 7);
    return (const short8*)(Vg + (long)row * Sc + (long)t * 64 + u * 8);
  };

  float rs[4][4] = {};

  // ---- Loop A (exact R6) ----
  short8 kr0 = *kaddr(0, 0), kr1 = *kaddr(0, 1), kr2_ = *kaddr(0, 2), kr3 = *kaddr(0, 3);
  for (int t = 0; t < 32; ++t) {
    __syncthreads();
    *(short8*)(&Ks[(0 * 4 + wave) * 512 + lane * 8]) = kr0;
    *(short8*)(&Ks[(1 * 4 + wave) * 512 + lane * 8]) = kr1;
    *(short8*)(&Ks[(2 * 4 + wave) * 512 + lane * 8]) = kr2_;
    *(short8*)(&Ks[(3 * 4 + wave) * 512 + lane * 8]) = kr3;
    {
      int tn = (t + 1) & 31;
      kr0 = *kaddr(tn, 0); kr1 = *kaddr(tn, 1);
      kr2_ = *kaddr(tn, 2); kr3 = *kaddr(tn, 3);
    }
    __syncthreads();
    f32x4 acc[4][2] = {};
    __builtin_amdgcn_s_setprio(1);
#pragma unroll
    for (int kk = 0; kk < 4; ++kk) {
      short8 af[4], bfr[2];
#pragma unroll
      for (int m = 0; m < 4; ++m) {
        int row = wr * 64 + m * 16 + (lane & 15);
        int p = (kk * 4 + (lane >> 4)) ^ (row & 15);
        af[m] = *(const short8*)(&Qs[row * 128 + p * 8]);
      }
#pragma unroll
      for (int nn = 0; nn < 2; ++nn) {
        int row = wc * 32 + nn * 16 + (lane & 15);
        int p = (kk * 4 + (lane >> 4)) ^ (row & 15);
        bfr[nn] = *(const short8*)(&Ks[row * 128 + p * 8]);
      }
#pragma unroll
      for (int m = 0; m < 4; ++m)
#pragma unroll
        for (int nn = 0; nn < 2; ++nn)
          acc[m][nn] = __builtin_amdgcn_mfma_f32_16x16x32_bf16(af[m], bfr[nn], acc[m][nn], 0, 0, 0);
    }
    __builtin_amdgcn_s_setprio(0);
#pragma unroll
    for (int m = 0; m < 4; ++m)
#pragma unroll
      for (int nn = 0; nn < 2; ++nn)
#pragma unroll
        for (int j = 0; j < 4; ++j)
          rs[m][j] += __expf(acc[m][nn][j] * SCALE);
  }

  // Loop B prologue loads issued early (hide under reduction)
  short8 k0 = *kaddr(0, 0), k1_ = *kaddr(0, 1), k2_ = *kaddr(0, 2), k3 = *kaddr(0, 3);
  short8 v0 = *vaddr(0, 0), v1 = *vaddr(0, 1), v2 = *vaddr(0, 2), v3 = *vaddr(0, 3);

  float* red = (float*)Ps;
#pragma unroll
  for (int m = 0; m < 4; ++m)
#pragma unroll
    for (int j = 0; j < 4; ++j) {
#pragma unroll
      for (int off = 1; off < 16; off <<= 1)
        rs[m][j] += __shfl_xor(rs[m][j], off);
    }
  __syncthreads();
  if ((lane & 15) == 0) {
#pragma unroll
    for (int m = 0; m < 4; ++m)
#pragma unroll
      for (int j = 0; j < 4; ++j)
        red[wc * 128 + wr * 64 + m * 16 + ((lane >> 4) * 4) + j] = rs[m][j];
  }
  __syncthreads();
  float invl[4][4];
#pragma unroll
  for (int m = 0; m < 4; ++m)
#pragma unroll
    for (int j = 0; j < 4; ++j) {
      int row = wr * 64 + m * 16 + ((lane >> 4) * 4) + j;
      invl[m][j] = 1.f / (red[row] + red[128 + row]);
    }

  // ---- Loop B (exact R6) ----
  f32x4 acco[4][4] = {};
  for (int t = 0; t < 32; ++t) {
    __syncthreads();
    *(short8*)(&Ks[(0 * 4 + wave) * 512 + lane * 8]) = k0;
    *(short8*)(&Ks[(1 * 4 + wave) * 512 + lane * 8]) = k1_;
    *(short8*)(&Ks[(2 * 4 + wave) * 512 + lane * 8]) = k2_;
    *(short8*)(&Ks[(3 * 4 + wave) * 512 + lane * 8]) = k3;
    *(short8*)(&Vs[(0 * 4 + wave) * 512 + lane * 8]) = v0;
    *(short8*)(&Vs[(1 * 4 + wave) * 512 + lane * 8]) = v1;
    *(short8*)(&Vs[(2 * 4 + wave) * 512 + lane * 8]) = v2;
    *(short8*)(&Vs[(3 * 4 + wave) * 512 + lane * 8]) = v3;
    {
      int tn = (t + 1) & 31;
      k0 = *kaddr(tn, 0); k1_ = *kaddr(tn, 1); k2_ = *kaddr(tn, 2); k3 = *kaddr(tn, 3);
      v0 = *vaddr(tn, 0); v1 = *vaddr(tn, 1); v2 = *vaddr(tn, 2); v3 = *vaddr(tn, 3);
    }
    __syncthreads();
    f32x4 acc[4][2] = {};
    __builtin_amdgcn_s_setprio(1);
#pragma unroll
    for (int kk = 0; kk < 4; ++kk) {
      short8 af[4], bfr[2];
#pragma unroll
      for (int m = 0; m < 4; ++m) {
        int row = wr * 64 + m * 16 + (lane & 15);
        int p = (kk * 4 + (lane >> 4)) ^ (row & 15);
        af[m] = *(const short8*)(&Qs[row * 128 + p * 8]);
      }
#pragma unroll
      for (int nn = 0; nn < 2; ++nn) {
        int row = wc * 32 + nn * 16 + (lane & 15);
        int p = (kk * 4 + (lane >> 4)) ^ (row & 15);
        bfr[nn] = *(const short8*)(&Ks[row * 128 + p * 8]);
      }
#pragma unroll
      for (int m = 0; m < 4; ++m)
#pragma unroll
        for (int nn = 0; nn < 2; ++nn)
          acc[m][nn] = __builtin_amdgcn_mfma_f32_16x16x32_bf16(af[m], bfr[nn], acc[m][nn], 0, 0, 0);
    }
    __builtin_amdgcn_s_setprio(0);
#pragma unroll
    for (int m = 0; m < 4; ++m) {
#pragma unroll
      for (int nn = 0; nn < 2; ++nn) {
#pragma unroll
        for (int j = 0; j < 4; ++j) {
          float e = __expf(acc[m][nn][j] * SCALE) * invl[m][j];
          int row = wr * 64 + m * 16 + ((lane >> 4) * 4) + j;
          int col = wc * 32 + nn * 16 + (lane & 15);
          __builtin_nontemporal_store(e, &Pg[(m0 + row) * (long)Sc + (long)t * 64 + col]);
          int pp = (col >> 3) ^ (row & 7);
          Ps[row * 64 + pp * 8 + (col & 7)] = (ushort_t)f2bf(e);
        }
      }
    }
    __syncthreads();
    __builtin_amdgcn_s_setprio(1);
#pragma unroll
    for (int ks = 0; ks < 2; ++ks) {
      short8 pa[4], vb[4];
#pragma unroll
      for (int m = 0; m < 4; ++m) {
        int row = wr * 64 + m * 16 + (lane & 15);
        int p = (ks * 4 + (lane >> 4)) ^ (row & 7);
        pa[m] = *(const short8*)(&Ps[row * 64 + p * 8]);
      }
#pragma unroll
      for (int nn = 0; nn < 4; ++nn) {
        int row = wc * 64 + nn * 16 + (lane & 15);
        int p = (ks * 4 + (lane >> 4)) ^ (row & 7);
        vb[nn] = *(const short8*)(&Vs[row * 64 + p * 8]);
      }
#pragma unroll
      for (int m = 0; m < 4; ++m)
#pragma unroll
        for (int nn = 0; nn < 4; ++nn)
          acco[m][nn] = __builtin_amdgcn_mfma_f32_16x16x32_bf16(pa[m], vb[nn], acco[m][nn], 0, 0, 0);
    }
    __builtin_amdgcn_s_setprio(0);
  }

#pragma unroll
  for (int m = 0; m < 4; ++m) {
#pragma unroll
    for (int nn = 0; nn < 4; ++nn) {
#pragma unroll
      for (int j = 0; j < 4; ++j) {
        int row = wr * 64 + m * 16 + ((lane >> 4) * 4) + j;
        int col = wc * 64 + nn * 16 + (lane & 15);
        Cb[((long)(n >> 4) * Sc + m0 + row) * (long)Dc + (long)(n & 15) * DKc + col] =
            (ushort_t)f2bf(acco[m][nn][j]);
      }
    }
  }
}

// ---------------------------------------------------------------------------
__global__ __launch_bounds__(256)
void castW_bf16(const float* __restrict__ w0, const float* __restrict__ w1,
                const float* __restrict__ w2, const float* __restrict__ w3,
                ushort_t* __restrict__ o0, ushort_t* __restrict__ o1,
                ushort_t* __restrict__ o2, ushort_t* __restrict__ o3) {
  const float* in; ushort_t* out;
  switch (blockIdx.y) {
    case 0: in = w0; out = o0; break;
    case 1: in = w1; out = o1; break;
    case 2: in = w2; out = o2; break;
    default: in = w3; out = o3; break;
  }
  long i = ((long)blockIdx.x * 256 + threadIdx.x) * 8;
  f32x4 x = *(const f32x4*)(in + i);
  f32x4 y = *(const f32x4*)(in + i + 4);
  *(short8*)(out + i) = pack8(x, y);
}

// in-place row layernorm on (8192, 2048) fp32
__global__ __launch_bounds__(256)
void layernorm_rows(float* __restrict__ out, const float* __restrict__ gamma,
                    const float* __restrict__ beta) {
  const long row = blockIdx.x;
  float* p = out + row * (long)Dc;
  const int tid = threadIdx.x;
  const int lane = tid & 63, wave = tid >> 6;
  f32x4 v0 = *(const f32x4*)(p + tid * 8);
  f32x4 v1 = *(const f32x4*)(p + tid * 8 + 4);
  float s = 0.f, ss = 0.f;
#pragma unroll
  for (int e = 0; e < 4; ++e) { s += v0[e]; ss += v0[e] * v0[e]; }
#pragma unroll
  for (int e = 0; e < 4; ++e) { s += v1[e]; ss += v1[e] * v1[e]; }
  for (int off = 32; off > 0; off >>= 1) { s += __shfl_xor(s, off); ss += __shfl_xor(ss, off); }
  __shared__ float rs_[4], rss_[4];
  if (lane == 0) { rs_[wave] = s; rss_[wave] = ss; }
  __syncthreads();
  s  = rs_[0] + rs_[1] + rs_[2] + rs_[3];
  ss = rss_[0] + rss_[1] + rss_[2] + rss_[3];
  const float mean = s * (1.f / Dc);
  const float var  = ss * (1.f / Dc) - mean * mean;
  const float rstd = rsqrtf(var + 1e-6f);
  f32x4 g0 = *(const f32x4*)(gamma + tid * 8);
  f32x4 g1 = *(const f32x4*)(gamma + tid * 8 + 4);
  f32x4 b0 = *(const f32x4*)(beta + tid * 8);
  f32x4 b1 = *(const f32x4*)(beta + tid * 8 + 4);
#pragma unroll
  for (int e = 0; e < 4; ++e) v0[e] = (v0[e] - mean) * rstd * g0[e] + b0[e];
#pragma unroll
  for (int e = 0; e < 4; ++e) v1[e] = (v1[e] - mean) * rstd * g1[e] + b1[e];
  *(f32x4*)(p + tid * 8) = v0;
  *(f32x4*)(p + tid * 8 + 4) = v1;
}

// ---------------------------------------------------------------------------
extern "C" void kernel_launch(void* const* d_in, const int* in_sizes, int n_in,
                              void* d_out, int out_size, void* d_ws, size_t ws_size,
                              hipStream_t stream) {
  (void)in_sizes; (void)n_in; (void)out_size; (void)ws_size;
  const float* q  = (const float*)d_in[0];
  const float* k  = (const float*)d_in[1];
  const float* v  = (const float*)d_in[2];
  const float* Wq = (const float*)d_in[3];
  const float* Wk = (const float*)d_in[4];
  const float* Wv = (const float*)d_in[5];
  const float* Wo = (const float*)d_in[6];
  const float* gamma = (const float*)d_in[7];
  const float* beta  = (const float*)d_in[8];

  float* out  = (float*)d_out;
  float* attn = out + OUT_ELEMS;                // 4.3 GB region (output 1)

  // workspace layout (~168 MB)
  ushort_t* Wqb = (ushort_t*)d_ws;
  ushort_t* Wkb = Wqb + (long)Dc * Dc;
  ushort_t* Wvb = Wkb + (long)Dc * Dc;
  ushort_t* Wob = Wvb + (long)Dc * Dc;
  ushort_t* Qb  = Wob + (long)Dc * Dc;
  ushort_t* Kb  = Qb + OUT_ELEMS;
  ushort_t* VT  = Kb + OUT_ELEMS;
  ushort_t* Cb  = VT + OUT_ELEMS;

  // weight casts (bf16 B operands)
  castW_bf16<<<dim3((long)Dc * Dc / 2048, 4), dim3(256), 0, stream>>>(
      Wq, Wk, Wv, Wo, Wqb, Wkb, Wvb, Wob);

  // fused 3-projection GEMM, fp32 A direct (grid.z = q/k/v)
  proj_gemm<<<dim3(8, 32, 3), dim3(512), 0, stream>>>(
      q, k, v, Wqb, Wkb, Wvb, Qb, Kb, VT);

  // flash attention (exact R6 + setprio)
  flash_attn<<<dim3(1024), dim3(256), 0, stream>>>(Qb, Kb, VT, attn, Cb);

  // output projection + residual
  out_gemm<<<dim3(8, 32), dim3(512), 0, stream>>>(Cb, Wob, out, q);

  // layernorm in place
  layernorm_rows<<<NTOK, dim3(256), 0, stream>>>(out, gamma, beta);
}

// Round 13
// 720.241 us; speedup vs baseline: 1.1293x; 1.1293x over previous
//
#include <hip/hip_runtime.h>
#include <cstdint>

typedef __attribute__((ext_vector_type(8))) short short8;
typedef __attribute__((ext_vector_type(4))) float f32x4;
typedef __attribute__((ext_vector_type(2))) unsigned u32x2;
typedef unsigned short ushort_t;

constexpr int Bc = 4, Sc = 2048, Dc = 2048, Hc = 16, DKc = 128;
constexpr long NTOK = (long)Bc * Sc;          // 8192 rows
constexpr long OUT_ELEMS = NTOK * (long)Dc;   // 16777216
constexpr float SCALE = 0.08838834764831843f; // 1/sqrt(128)

__device__ __forceinline__ ushort_t f2bf(float f) {
  unsigned u = __builtin_bit_cast(unsigned, f);
  u = (u + 0x7FFFu + ((u >> 16) & 1u)) >> 16;
  return (ushort_t)u;
}

__device__ __forceinline__ short8 pack8(const f32x4& a, const f32x4& b) {
  short8 h;
  h[0] = (short)f2bf(a[0]); h[1] = (short)f2bf(a[1]);
  h[2] = (short)f2bf(a[2]); h[3] = (short)f2bf(a[3]);
  h[4] = (short)f2bf(b[0]); h[5] = (short)f2bf(b[1]);
  h[6] = (short)f2bf(b[2]); h[7] = (short)f2bf(b[3]);
  return h;
}

// async global->LDS, 16B per lane; lds dest is wave-uniform base + lane*16
__device__ __forceinline__ void gl2lds16(const ushort_t* g, ushort_t* l) {
  __builtin_amdgcn_global_load_lds(
      (__attribute__((address_space(1))) unsigned int*)(g),
      (__attribute__((address_space(3))) unsigned int*)(l), 16, 0, 0);
}

__device__ __forceinline__ void bar() {
  asm volatile("" ::: "memory");
  __builtin_amdgcn_s_barrier();
  asm volatile("" ::: "memory");
}

// ---------------------------------------------------------------------------
// Fused 3-projection GEMM, fp32 A source. C = A(8192x2048 fp32)*W(2048x2048)^T.
// 256x256 tile, BK=64, 512 thr (8 waves 2Mx4N), dbuf 128KB LDS.
// z=0: Q proj, z=1: K proj, z=2: V proj -> VT transposed.
// ---------------------------------------------------------------------------
__global__ __launch_bounds__(512, 2)
void proj_gemm(const float* __restrict__ qf, const float* __restrict__ kf,
               const float* __restrict__ vf,
               const ushort_t* __restrict__ Wqb, const ushort_t* __restrict__ Wkb,
               const ushort_t* __restrict__ Wvb,
               ushort_t* __restrict__ Qb, ushort_t* __restrict__ Kb,
               ushort_t* __restrict__ VTo)
{
  __shared__ __align__(16) ushort_t SM[2][2][2][128 * 64]; // [A/B][buf][half]

  const int z = blockIdx.z;
  const float* Afull = (z == 0) ? qf : (z == 1) ? kf : vf;
  const ushort_t* Bp = (z == 0) ? Wqb : (z == 1) ? Wkb : Wvb;
  ushort_t* Cp = (z == 0) ? Qb : (z == 1) ? Kb : VTo;

  const int tid = threadIdx.x, lane = tid & 63, wave = tid >> 6;
  const int wm = wave >> 2, wn = wave & 3;

  const int lin = blockIdx.y * 8 + blockIdx.x;
  const int swz = (lin & 7) * 32 + (lin >> 3);
  const long n0 = (long)(swz & 7) * 256;
  const long m0 = (long)(swz >> 3) * 256;

  constexpr int NT = 32;

  const float*    Ag = Afull + m0 * (long)Dc;
  const ushort_t* Bg = Bp + n0 * (long)Dc;

  auto stageB = [&](ushort_t* dst, int kt, int ht) {
#pragma unroll
    for (int c = 0; c < 2; ++c) {
      int U = (c * 8 + wave) * 64 + lane;
      int row = U >> 3, p = U & 7, u = p ^ (row & 7);
      gl2lds16(Bg + (long)(ht * 128 + row) * Dc + kt * 64 + u * 8,
               dst + (c * 8 + wave) * 512);
    }
  };
  auto loadA = [&](int kt, f32x4 alo[2][2], f32x4 ahi[2][2]) {
#pragma unroll
    for (int ht = 0; ht < 2; ++ht)
#pragma unroll
      for (int c = 0; c < 2; ++c) {
        int U = (c * 8 + wave) * 64 + lane;
        int row = U >> 3, p = U & 7, u = p ^ (row & 7);
        const float* g = Ag + (long)(ht * 128 + row) * Dc + kt * 64 + u * 8;
        alo[ht][c] = *(const f32x4*)g;
        ahi[ht][c] = *(const f32x4*)(g + 4);
      }
  };
  auto writeA = [&](int buf, const f32x4 alo[2][2], const f32x4 ahi[2][2]) {
#pragma unroll
    for (int ht = 0; ht < 2; ++ht)
#pragma unroll
      for (int c = 0; c < 2; ++c) {
        int chunk = c * 8 + wave;
        *(short8*)(&SM[0][buf][ht][chunk * 512 + lane * 8]) =
            pack8(alo[ht][c], ahi[ht][c]);
      }
  };

  stageB(&SM[1][0][0][0], 0, 0);
  stageB(&SM[1][0][1][0], 0, 1);
  stageB(&SM[1][1][0][0], 1, 0);
  {
    f32x4 alo[2][2], ahi[2][2];
    loadA(0, alo, ahi);
    asm volatile("s_waitcnt vmcnt(0)" ::: "memory");
    writeA(0, alo, ahi);
    asm volatile("s_waitcnt lgkmcnt(0)" ::: "memory");
  }
  __builtin_amdgcn_s_barrier();
  asm volatile("" ::: "memory");

  f32x4 acc[8][4] = {};

  for (int kt = 0; kt < NT; ++kt) {
    const int cur = kt & 1;
    const ushort_t* Acur = &SM[0][cur][0][0];
    const ushort_t* Bcur = &SM[1][cur][0][0];
    const int k1 = (kt + 1) & (NT - 1);
    const int k2 = (kt + 2) & (NT - 1);
    short8 af[4][2], bq0[2][2], bq1[2][2];
    f32x4 alo[2][2], ahi[2][2];

    // P0
#pragma unroll
    for (int mf = 0; mf < 4; ++mf)
#pragma unroll
      for (int ks = 0; ks < 2; ++ks) {
        int r = mf * 16 + (lane & 15);
        int u = ks * 4 + (lane >> 4), p = u ^ (r & 7);
        af[mf][ks] = *(const short8*)(Acur + wm * (128 * 64) + r * 64 + p * 8);
      }
#pragma unroll
    for (int nf = 0; nf < 2; ++nf)
#pragma unroll
      for (int ks = 0; ks < 2; ++ks) {
        int r = (wn & 1) * 64 + nf * 16 + (lane & 15);
        int u = ks * 4 + (lane >> 4), p = u ^ (r & 7);
        bq0[nf][ks] = *(const short8*)(Bcur + (wn >> 1) * (128 * 64) + r * 64 + p * 8);
      }
    stageB(&SM[1][cur ^ 1][1][0], k1, 1);
    bar();
    __builtin_amdgcn_s_setprio(1);
#pragma unroll
    for (int mf = 0; mf < 4; ++mf)
#pragma unroll
      for (int nf = 0; nf < 2; ++nf)
#pragma unroll
        for (int ks = 0; ks < 2; ++ks)
          acc[mf][nf] = __builtin_amdgcn_mfma_f32_16x16x32_bf16(af[mf][ks], bq0[nf][ks], acc[mf][nf], 0, 0, 0);
    __builtin_amdgcn_s_setprio(0);
    bar();

    // P1
#pragma unroll
    for (int nf = 0; nf < 2; ++nf)
#pragma unroll
      for (int ks = 0; ks < 2; ++ks) {
        int r = (wn & 1) * 64 + 32 + nf * 16 + (lane & 15);
        int u = ks * 4 + (lane >> 4), p = u ^ (r & 7);
        bq1[nf][ks] = *(const short8*)(Bcur + (wn >> 1) * (128 * 64) + r * 64 + p * 8);
      }
    loadA(k1, alo, ahi);
    bar();
    __builtin_amdgcn_s_setprio(1);
#pragma unroll
    for (int mf = 0; mf < 4; ++mf)
#pragma unroll
      for (int nf = 0; nf < 2; ++nf)
#pragma unroll
        for (int ks = 0; ks < 2; ++ks)
          acc[mf][2 + nf] = __builtin_amdgcn_mfma_f32_16x16x32_bf16(af[mf][ks], bq1[nf][ks], acc[mf][2 + nf], 0, 0, 0);
    __builtin_amdgcn_s_setprio(0);
    bar();

    // P2
#pragma unroll
    for (int mf = 0; mf < 4; ++mf)
#pragma unroll
      for (int ks = 0; ks < 2; ++ks) {
        int r = 64 + mf * 16 + (lane & 15);
        int u = ks * 4 + (lane >> 4), p = u ^ (r & 7);
        af[mf][ks] = *(const short8*)(Acur + wm * (128 * 64) + r * 64 + p * 8);
      }
    stageB(&SM[1][cur][0][0], k2, 0);
    bar();
    __builtin_amdgcn_s_setprio(1);
#pragma unroll
    for (int mf = 0; mf < 4; ++mf)
#pragma unroll
      for (int nf = 0; nf < 2; ++nf)
#pragma unroll
        for (int ks = 0; ks < 2; ++ks)
          acc[4 + mf][nf] = __builtin_amdgcn_mfma_f32_16x16x32_bf16(af[mf][ks], bq0[nf][ks], acc[4 + mf][nf], 0, 0, 0);
    __builtin_amdgcn_s_setprio(0);
    bar();

    // P3
    asm volatile("s_waitcnt vmcnt(2)" ::: "memory");
    writeA(cur ^ 1, alo, ahi);
    asm volatile("s_waitcnt lgkmcnt(0)" ::: "memory");
    bar();
    __builtin_amdgcn_s_setprio(1);
#pragma unroll
    for (int mf = 0; mf < 4; ++mf)
#pragma unroll
      for (int nf = 0; nf < 2; ++nf)
#pragma unroll
        for (int ks = 0; ks < 2; ++ks)
          acc[4 + mf][2 + nf] = __builtin_amdgcn_mfma_f32_16x16x32_bf16(af[mf][ks], bq1[nf][ks], acc[4 + mf][2 + nf], 0, 0, 0);
    __builtin_amdgcn_s_setprio(0);
    bar();
  }

  asm volatile("s_waitcnt vmcnt(0)" ::: "memory");

  if (z == 2) {
    bar();
    char* Tb = (char*)&SM[0][0][0][0];    // 256 rows(cg) x 512B(rg), XOR-swz
#pragma unroll
    for (int mq = 0; mq < 8; ++mq) {
#pragma unroll
      for (int nq = 0; nq < 4; ++nq) {
        int rg = wm * 128 + (mq >> 2) * 64 + (mq & 3) * 16 + ((lane >> 4) * 4);
        int cg = wn * 64 + (nq >> 1) * 32 + (nq & 1) * 16 + (lane & 15);
        u32x2 t;
        t[0] = (unsigned)f2bf(acc[mq][nq][0]) | ((unsigned)f2bf(acc[mq][nq][1]) << 16);
        t[1] = (unsigned)f2bf(acc[mq][nq][2]) | ((unsigned)f2bf(acc[mq][nq][3]) << 16);
        int off = cg * 512 + (((rg >> 3) ^ (cg & 31)) * 16) + (rg & 7) * 2;
        *(u32x2*)(Tb + off) = t;
      }
    }
    bar();
    const long bq = m0 >> 11;
    const long s0 = m0 & 2047;
#pragma unroll
    for (int i = 0; i < 16; ++i) {
      int row = i * 16 + (tid >> 5);
      int un  = tid & 31;
      int p = un ^ (row & 31);
      short8 val = *(const short8*)(Tb + row * 512 + p * 16);
      long cgg = n0 + row;
      long vtrow = ((cgg >> 7) * 4 + bq) * 128 + (cgg & 127);
      *(short8*)(&Cp[vtrow * (long)Sc + s0 + un * 8]) = val;
    }
  } else {
#pragma unroll
    for (int mq = 0; mq < 8; ++mq) {
#pragma unroll
      for (int nq = 0; nq < 4; ++nq) {
#pragma unroll
        for (int j = 0; j < 4; ++j) {
          long rg = m0 + wm * 128 + (mq >> 2) * 64 + (mq & 3) * 16 + ((lane >> 4) * 4) + j;
          long cg = n0 + wn * 64 + (nq >> 1) * 32 + (nq & 1) * 16 + (lane & 15);
          Cp[rg * (long)Dc + cg] = f2bf(acc[mq][nq][j]);
        }
      }
    }
  }
}

// ---------------------------------------------------------------------------
// Output-projection GEMM (bf16 A via gl2lds), 256x256 8-phase, fp32 C+residual.
// ---------------------------------------------------------------------------
__global__ __launch_bounds__(512, 2)
void out_gemm(const ushort_t* __restrict__ Ap, const ushort_t* __restrict__ Bp,
              float* __restrict__ Cp, const float* __restrict__ residual)
{
  __shared__ __align__(16) ushort_t SM[2][2][2][128 * 64];

  const int tid = threadIdx.x, lane = tid & 63, wave = tid >> 6;
  const int wm = wave >> 2, wn = wave & 3;
  const int lin = blockIdx.y * 8 + blockIdx.x;
  const int swz = (lin & 7) * 32 + (lin >> 3);
  const long n0 = (long)(swz & 7) * 256;
  const long m0 = (long)(swz >> 3) * 256;
  constexpr int NT = 32;

  const ushort_t* Ag = Ap + m0 * (long)Dc;
  const ushort_t* Bg = Bp + n0 * (long)Dc;

  auto stage = [&](const ushort_t* gb, ushort_t* dst, int kt, int ht) {
#pragma unroll
    for (int c = 0; c < 2; ++c) {
      int U = (c * 8 + wave) * 64 + lane;
      int row = U >> 3, p = U & 7, u = p ^ (row & 7);
      gl2lds16(gb + (long)(ht * 128 + row) * Dc + kt * 64 + u * 8,
               dst + (c * 8 + wave) * 512);
    }
  };

  stage(Bg, &SM[1][0][0][0], 0, 0);
  stage(Ag, &SM[0][0][0][0], 0, 0);
  stage(Bg, &SM[1][0][1][0], 0, 1);
  stage(Ag, &SM[0][0][1][0], 0, 1);
  stage(Bg, &SM[1][1][0][0], 1, 0);
  stage(Ag, &SM[0][1][0][0], 1, 0);
  asm volatile("s_waitcnt vmcnt(4)" ::: "memory");
  __builtin_amdgcn_s_barrier();
  asm volatile("" ::: "memory");

  f32x4 acc[8][4] = {};

  for (int kt = 0; kt < NT; ++kt) {
    const int cur = kt & 1;
    const ushort_t* Acur = &SM[0][cur][0][0];
    const ushort_t* Bcur = &SM[1][cur][0][0];
    const int k1 = (kt + 1) & (NT - 1);
    const int k2 = (kt + 2) & (NT - 1);
    short8 af[4][2], bq0[2][2], bq1[2][2];

#pragma unroll
    for (int mf = 0; mf < 4; ++mf)
#pragma unroll
      for (int ks = 0; ks < 2; ++ks) {
        int r = mf * 16 + (lane & 15);
        int u = ks * 4 + (lane >> 4), p = u ^ (r & 7);
        af[mf][ks] = *(const short8*)(Acur + wm * (128 * 64) + r * 64 + p * 8);
      }
#pragma unroll
    for (int nf = 0; nf < 2; ++nf)
#pragma unroll
      for (int ks = 0; ks < 2; ++ks) {
        int r = (wn & 1) * 64 + nf * 16 + (lane & 15);
        int u = ks * 4 + (lane >> 4), p = u ^ (r & 7);
        bq0[nf][ks] = *(const short8*)(Bcur + (wn >> 1) * (128 * 64) + r * 64 + p * 8);
      }
    stage(Bg, &SM[1][cur ^ 1][1][0], k1, 1);
    bar();
    __builtin_amdgcn_s_setprio(1);
#pragma unroll
    for (int mf = 0; mf < 4; ++mf)
#pragma unroll
      for (int nf = 0; nf < 2; ++nf)
#pragma unroll
        for (int ks = 0; ks < 2; ++ks)
          acc[mf][nf] = __builtin_amdgcn_mfma_f32_16x16x32_bf16(af[mf][ks], bq0[nf][ks], acc[mf][nf], 0, 0, 0);
    __builtin_amdgcn_s_setprio(0);
    bar();

#pragma unroll
    for (int nf = 0; nf < 2; ++nf)
#pragma unroll
      for (int ks = 0; ks < 2; ++ks) {
        int r = (wn & 1) * 64 + 32 + nf * 16 + (lane & 15);
        int u = ks * 4 + (lane >> 4), p = u ^ (r & 7);
        bq1[nf][ks] = *(const short8*)(Bcur + (wn >> 1) * (128 * 64) + r * 64 + p * 8);
      }
    stage(Ag, &SM[0][cur ^ 1][1][0], k1, 1);
    bar();
    __builtin_amdgcn_s_setprio(1);
#pragma unroll
    for (int mf = 0; mf < 4; ++mf)
#pragma unroll
      for (int nf = 0; nf < 2; ++nf)
#pragma unroll
        for (int ks = 0; ks < 2; ++ks)
          acc[mf][2 + nf] = __builtin_amdgcn_mfma_f32_16x16x32_bf16(af[mf][ks], bq1[nf][ks], acc[mf][2 + nf], 0, 0, 0);
    __builtin_amdgcn_s_setprio(0);
    bar();

#pragma unroll
    for (int mf = 0; mf < 4; ++mf)
#pragma unroll
      for (int ks = 0; ks < 2; ++ks) {
        int r = 64 + mf * 16 + (lane & 15);
        int u = ks * 4 + (lane >> 4), p = u ^ (r & 7);
        af[mf][ks] = *(const short8*)(Acur + wm * (128 * 64) + r * 64 + p * 8);
      }
    stage(Bg, &SM[1][cur][0][0], k2, 0);
    bar();
    __builtin_amdgcn_s_setprio(1);
#pragma unroll
    for (int mf = 0; mf < 4; ++mf)
#pragma unroll
      for (int nf = 0; nf < 2; ++nf)
#pragma unroll
        for (int ks = 0; ks < 2; ++ks)
          acc[4 + mf][nf] = __builtin_amdgcn_mfma_f32_16x16x32_bf16(af[mf][ks], bq0[nf][ks], acc[4 + mf][nf], 0, 0, 0);
    __builtin_amdgcn_s_setprio(0);
    bar();

    stage(Ag, &SM[0][cur][0][0], k2, 0);
    asm volatile("s_waitcnt vmcnt(4)" ::: "memory");
    bar();
    __builtin_amdgcn_s_setprio(1);
#pragma unroll
    for (int mf = 0; mf < 4; ++mf)
#pragma unroll
      for (int nf = 0; nf < 2; ++nf)
#pragma unroll
        for (int ks = 0; ks < 2; ++ks)
          acc[4 + mf][2 + nf] = __builtin_amdgcn_mfma_f32_16x16x32_bf16(af[mf][ks], bq1[nf][ks], acc[4 + mf][2 + nf], 0, 0, 0);
    __builtin_amdgcn_s_setprio(0);
    bar();
  }

  asm volatile("s_waitcnt vmcnt(0)" ::: "memory");

#pragma unroll
  for (int mq = 0; mq < 8; ++mq) {
#pragma unroll
    for (int nq = 0; nq < 4; ++nq) {
#pragma unroll
      for (int j = 0; j < 4; ++j) {
        long rg = m0 + wm * 128 + (mq >> 2) * 64 + (mq & 3) * 16 + ((lane >> 4) * 4) + j;
        long cg = n0 + wn * 64 + (nq >> 1) * 32 + (nq & 1) * 16 + (lane & 15);
        Cp[rg * (long)Dc + cg] = acc[mq][nq][j] + residual[rg * (long)Dc + cg];
      }
    }
  }
}

// ---------------------------------------------------------------------------
// Flash attention (R6 exact, best known): K/V reg-staged, t+1 loads issued
// BEFORE the 2nd __syncthreads; nontemporal P stores; no setprio.
// LDS: Qs 32K + Ks 16K + Vs 16K + Ps 16K = 80KB -> 2 blocks/CU.
// ---------------------------------------------------------------------------
__global__ __launch_bounds__(256, 2)
void flash_attn(const ushort_t* __restrict__ Qb, const ushort_t* __restrict__ Kb,
                const ushort_t* __restrict__ VT, float* __restrict__ attn,
                ushort_t* __restrict__ Cb)
{
  __shared__ __align__(16) ushort_t Qs[128 * 128]; // swz u^(row&15)
  __shared__ __align__(16) ushort_t Ks[64 * 128];  // swz u^(row&15)
  __shared__ __align__(16) ushort_t Vs[128 * 64];  // swz u^(row&7)
  __shared__ __align__(16) ushort_t Ps[128 * 64];  // swz u^(row&7)

  const int tid = threadIdx.x, lane = tid & 63, wave = tid >> 6;
  const int wr = wave >> 1, wc = wave & 1;

  const int bid = blockIdx.x;
  const int xcd = bid & 7, slot = bid >> 3;
  const int n = xcd * 8 + (slot >> 4);
  const long m0 = (long)(slot & 15) * 128;
  const int b = n & 3, h = n >> 2;

  const ushort_t* Qg = Qb + ((long)b * Sc) * Dc + (long)h * DKc;
  const ushort_t* Kg = Kb + ((long)b * Sc) * Dc + (long)h * DKc;
  const ushort_t* Vg = VT + (long)n * DKc * (long)Sc;
  float* Pg = attn + (long)n * Sc * (long)Sc;

#pragma unroll
  for (int c8 = 0; c8 < 8; ++c8) {
    int chunk = c8 * 4 + wave;
    int U = chunk * 64 + lane;
    int row = U >> 4, p = U & 15, u = p ^ (row & 15);
    gl2lds16(Qg + (m0 + row) * (long)Dc + u * 8, &Qs[chunk * 512]);
  }

  auto kaddr = [&](int t, int c4) -> const short8* {
    int chunk = c4 * 4 + wave;
    int U = chunk * 64 + lane;
    int row = U >> 4, p = U & 15, u = p ^ (row & 15);
    return (const short8*)(Kg + ((long)t * 64 + row) * (long)Dc + u * 8);
  };
  auto vaddr = [&](int t, int c4) -> const short8* {
    int chunk = c4 * 4 + wave;
    int U = chunk * 64 + lane;
    int row = U >> 3, p = U & 7, u = p ^ (row & 7);
    return (const short8*)(Vg + (long)row * Sc + (long)t * 64 + u * 8);
  };

  float rs[4][4] = {};

  // ---- Loop A ----
  short8 kr0 = *kaddr(0, 0), kr1 = *kaddr(0, 1), kr2_ = *kaddr(0, 2), kr3 = *kaddr(0, 3);
  for (int t = 0; t < 32; ++t) {
    __syncthreads();
    *(short8*)(&Ks[(0 * 4 + wave) * 512 + lane * 8]) = kr0;
    *(short8*)(&Ks[(1 * 4 + wave) * 512 + lane * 8]) = kr1;
    *(short8*)(&Ks[(2 * 4 + wave) * 512 + lane * 8]) = kr2_;
    *(short8*)(&Ks[(3 * 4 + wave) * 512 + lane * 8]) = kr3;
    {
      int tn = (t + 1) & 31;
      kr0 = *kaddr(tn, 0); kr1 = *kaddr(tn, 1);
      kr2_ = *kaddr(tn, 2); kr3 = *kaddr(tn, 3);
    }
    __syncthreads();
    f32x4 acc[4][2] = {};
#pragma unroll
    for (int kk = 0; kk < 4; ++kk) {
      short8 af[4], bfr[2];
#pragma unroll
      for (int m = 0; m < 4; ++m) {
        int row = wr * 64 + m * 16 + (lane & 15);
        int p = (kk * 4 + (lane >> 4)) ^ (row & 15);
        af[m] = *(const short8*)(&Qs[row * 128 + p * 8]);
      }
#pragma unroll
      for (int nn = 0; nn < 2; ++nn) {
        int row = wc * 32 + nn * 16 + (lane & 15);
        int p = (kk * 4 + (lane >> 4)) ^ (row & 15);
        bfr[nn] = *(const short8*)(&Ks[row * 128 + p * 8]);
      }
#pragma unroll
      for (int m = 0; m < 4; ++m)
#pragma unroll
        for (int nn = 0; nn < 2; ++nn)
          acc[m][nn] = __builtin_amdgcn_mfma_f32_16x16x32_bf16(af[m], bfr[nn], acc[m][nn], 0, 0, 0);
    }
#pragma unroll
    for (int m = 0; m < 4; ++m)
#pragma unroll
      for (int nn = 0; nn < 2; ++nn)
#pragma unroll
        for (int j = 0; j < 4; ++j)
          rs[m][j] += __expf(acc[m][nn][j] * SCALE);
  }

  // Loop B prologue loads issued early (hide under reduction)
  short8 k0 = *kaddr(0, 0), k1_ = *kaddr(0, 1), k2_ = *kaddr(0, 2), k3 = *kaddr(0, 3);
  short8 v0 = *vaddr(0, 0), v1 = *vaddr(0, 1), v2 = *vaddr(0, 2), v3 = *vaddr(0, 3);

  float* red = (float*)Ps;
#pragma unroll
  for (int m = 0; m < 4; ++m)
#pragma unroll
    for (int j = 0; j < 4; ++j) {
#pragma unroll
      for (int off = 1; off < 16; off <<= 1)
        rs[m][j] += __shfl_xor(rs[m][j], off);
    }
  __syncthreads();
  if ((lane & 15) == 0) {
#pragma unroll
    for (int m = 0; m < 4; ++m)
#pragma unroll
      for (int j = 0; j < 4; ++j)
        red[wc * 128 + wr * 64 + m * 16 + ((lane >> 4) * 4) + j] = rs[m][j];
  }
  __syncthreads();
  float invl[4][4];
#pragma unroll
  for (int m = 0; m < 4; ++m)
#pragma unroll
    for (int j = 0; j < 4; ++j) {
      int row = wr * 64 + m * 16 + ((lane >> 4) * 4) + j;
      invl[m][j] = 1.f / (red[row] + red[128 + row]);
    }

  // ---- Loop B ----
  f32x4 acco[4][4] = {};
  for (int t = 0; t < 32; ++t) {
    __syncthreads();
    *(short8*)(&Ks[(0 * 4 + wave) * 512 + lane * 8]) = k0;
    *(short8*)(&Ks[(1 * 4 + wave) * 512 + lane * 8]) = k1_;
    *(short8*)(&Ks[(2 * 4 + wave) * 512 + lane * 8]) = k2_;
    *(short8*)(&Ks[(3 * 4 + wave) * 512 + lane * 8]) = k3;
    *(short8*)(&Vs[(0 * 4 + wave) * 512 + lane * 8]) = v0;
    *(short8*)(&Vs[(1 * 4 + wave) * 512 + lane * 8]) = v1;
    *(short8*)(&Vs[(2 * 4 + wave) * 512 + lane * 8]) = v2;
    *(short8*)(&Vs[(3 * 4 + wave) * 512 + lane * 8]) = v3;
    {
      int tn = (t + 1) & 31;
      k0 = *kaddr(tn, 0); k1_ = *kaddr(tn, 1); k2_ = *kaddr(tn, 2); k3 = *kaddr(tn, 3);
      v0 = *vaddr(tn, 0); v1 = *vaddr(tn, 1); v2 = *vaddr(tn, 2); v3 = *vaddr(tn, 3);
    }
    __syncthreads();
    f32x4 acc[4][2] = {};
#pragma unroll
    for (int kk = 0; kk < 4; ++kk) {
      short8 af[4], bfr[2];
#pragma unroll
      for (int m = 0; m < 4; ++m) {
        int row = wr * 64 + m * 16 + (lane & 15);
        int p = (kk * 4 + (lane >> 4)) ^ (row & 15);
        af[m] = *(const short8*)(&Qs[row * 128 + p * 8]);
      }
#pragma unroll
      for (int nn = 0; nn < 2; ++nn) {
        int row = wc * 32 + nn * 16 + (lane & 15);
        int p = (kk * 4 + (lane >> 4)) ^ (row & 15);
        bfr[nn] = *(const short8*)(&Ks[row * 128 + p * 8]);
      }
#pragma unroll
      for (int m = 0; m < 4; ++m)
#pragma unroll
        for (int nn = 0; nn < 2; ++nn)
          acc[m][nn] = __builtin_amdgcn_mfma_f32_16x16x32_bf16(af[m], bfr[nn], acc[m][nn], 0, 0, 0);
    }
#pragma unroll
    for (int m = 0; m < 4; ++m) {
#pragma unroll
      for (int nn = 0; nn < 2; ++nn) {
#pragma unroll
        for (int j = 0; j < 4; ++j) {
          float e = __expf(acc[m][nn][j] * SCALE) * invl[m][j];
          int row = wr * 64 + m * 16 + ((lane >> 4) * 4) + j;
          int col = wc * 32 + nn * 16 + (lane & 15);
          __builtin_nontemporal_store(e, &Pg[(m0 + row) * (long)Sc + (long)t * 64 + col]);
          int pp = (col >> 3) ^ (row & 7);
          Ps[row * 64 + pp * 8 + (col & 7)] = (ushort_t)f2bf(e);
        }
      }
    }
    __syncthreads();
#pragma unroll
    for (int ks = 0; ks < 2; ++ks) {
      short8 pa[4], vb[4];
#pragma unroll
      for (int m = 0; m < 4; ++m) {
        int row = wr * 64 + m * 16 + (lane & 15);
        int p = (ks * 4 + (lane >> 4)) ^ (row & 7);
        pa[m] = *(const short8*)(&Ps[row * 64 + p * 8]);
      }
#pragma unroll
      for (int nn = 0; nn < 4; ++nn) {
        int row = wc * 64 + nn * 16 + (lane & 15);
        int p = (ks * 4 + (lane >> 4)) ^ (row & 7);
        vb[nn] = *(const short8*)(&Vs[row * 64 + p * 8]);
      }
#pragma unroll
      for (int m = 0; m < 4; ++m)
#pragma unroll
        for (int nn = 0; nn < 4; ++nn)
          acco[m][nn] = __builtin_amdgcn_mfma_f32_16x16x32_bf16(pa[m], vb[nn], acco[m][nn], 0, 0, 0);
    }
  }

#pragma unroll
  for (int m = 0; m < 4; ++m) {
#pragma unroll
    for (int nn = 0; nn < 4; ++nn) {
#pragma unroll
      for (int j = 0; j < 4; ++j) {
        int row = wr * 64 + m * 16 + ((lane >> 4) * 4) + j;
        int col = wc * 64 + nn * 16 + (lane & 15);
        Cb[((long)(n >> 4) * Sc + m0 + row) * (long)Dc + (long)(n & 15) * DKc + col] =
            (ushort_t)f2bf(acco[m][nn][j]);
      }
    }
  }
}

// ---------------------------------------------------------------------------
__global__ __launch_bounds__(256)
void castW_bf16(const float* __restrict__ w0, const float* __restrict__ w1,
                const float* __restrict__ w2, const float* __restrict__ w3,
                ushort_t* __restrict__ o0, ushort_t* __restrict__ o1,
                ushort_t* __restrict__ o2, ushort_t* __restrict__ o3) {
  const float* in; ushort_t* out;
  switch (blockIdx.y) {
    case 0: in = w0; out = o0; break;
    case 1: in = w1; out = o1; break;
    case 2: in = w2; out = o2; break;
    default: in = w3; out = o3; break;
  }
  long i = ((long)blockIdx.x * 256 + threadIdx.x) * 8;
  f32x4 x = *(const f32x4*)(in + i);
  f32x4 y = *(const f32x4*)(in + i + 4);
  *(short8*)(out + i) = pack8(x, y);
}

// in-place row layernorm on (8192, 2048) fp32
__global__ __launch_bounds__(256)
void layernorm_rows(float* __restrict__ out, const float* __restrict__ gamma,
                    const float* __restrict__ beta) {
  const long row = blockIdx.x;
  float* p = out + row * (long)Dc;
  const int tid = threadIdx.x;
  const int lane = tid & 63, wave = tid >> 6;
  f32x4 v0 = *(const f32x4*)(p + tid * 8);
  f32x4 v1 = *(const f32x4*)(p + tid * 8 + 4);
  float s = 0.f, ss = 0.f;
#pragma unroll
  for (int e = 0; e < 4; ++e) { s += v0[e]; ss += v0[e] * v0[e]; }
#pragma unroll
  for (int e = 0; e < 4; ++e) { s += v1[e]; ss += v1[e] * v1[e]; }
  for (int off = 32; off > 0; off >>= 1) { s += __shfl_xor(s, off); ss += __shfl_xor(ss, off); }
  __shared__ float rs_[4], rss_[4];
  if (lane == 0) { rs_[wave] = s; rss_[wave] = ss; }
  __syncthreads();
  s  = rs_[0] + rs_[1] + rs_[2] + rs_[3];
  ss = rss_[0] + rss_[1] + rss_[2] + rss_[3];
  const float mean = s * (1.f / Dc);
  const float var  = ss * (1.f / Dc) - mean * mean;
  const float rstd = rsqrtf(var + 1e-6f);
  f32x4 g0 = *(const f32x4*)(gamma + tid * 8);
  f32x4 g1 = *(const f32x4*)(gamma + tid * 8 + 4);
  f32x4 b0 = *(const f32x4*)(beta + tid * 8);
  f32x4 b1 = *(const f32x4*)(beta + tid * 8 + 4);
#pragma unroll
  for (int e = 0; e < 4; ++e) v0[e] = (v0[e] - mean) * rstd * g0[e] + b0[e];
#pragma unroll
  for (int e = 0; e < 4; ++e) v1[e] = (v1[e] - mean) * rstd * g1[e] + b1[e];
  *(f32x4*)(p + tid * 8) = v0;
  *(f32x4*)(p + tid * 8 + 4) = v1;
}

// ---------------------------------------------------------------------------
extern "C" void kernel_launch(void* const* d_in, const int* in_sizes, int n_in,
                              void* d_out, int out_size, void* d_ws, size_t ws_size,
                              hipStream_t stream) {
  (void)in_sizes; (void)n_in; (void)out_size; (void)ws_size;
  const float* q  = (const float*)d_in[0];
  const float* k  = (const float*)d_in[1];
  const float* v  = (const float*)d_in[2];
  const float* Wq = (const float*)d_in[3];
  const float* Wk = (const float*)d_in[4];
  const float* Wv = (const float*)d_in[5];
  const float* Wo = (const float*)d_in[6];
  const float* gamma = (const float*)d_in[7];
  const float* beta  = (const float*)d_in[8];

  float* out  = (float*)d_out;
  float* attn = out + OUT_ELEMS;                // 4.3 GB region (output 1)

  // workspace layout (~168 MB)
  ushort_t* Wqb = (ushort_t*)d_ws;
  ushort_t* Wkb = Wqb + (long)Dc * Dc;
  ushort_t* Wvb = Wkb + (long)Dc * Dc;
  ushort_t* Wob = Wvb + (long)Dc * Dc;
  ushort_t* Qb  = Wob + (long)Dc * Dc;
  ushort_t* Kb  = Qb + OUT_ELEMS;
  ushort_t* VT  = Kb + OUT_ELEMS;
  ushort_t* Cb  = VT + OUT_ELEMS;

  // weight casts (bf16 B operands)
  castW_bf16<<<dim3((long)Dc * Dc / 2048, 4), dim3(256), 0, stream>>>(
      Wq, Wk, Wv, Wo, Wqb, Wkb, Wvb, Wob);

  // fused 3-projection GEMM, fp32 A direct (grid.z = q/k/v)
  proj_gemm<<<dim3(8, 32, 3), dim3(512), 0, stream>>>(
      q, k, v, Wqb, Wkb, Wvb, Qb, Kb, VT);

  // flash attention (R6 exact, best known)
  flash_attn<<<dim3(1024), dim3(256), 0, stream>>>(Qb, Kb, VT, attn, Cb);

  // output projection + residual
  out_gemm<<<dim3(8, 32), dim3(512), 0, stream>>>(Cb, Wob, out, q);

  // layernorm in place
  layernorm_rows<<<NTOK, dim3(256), 0, stream>>>(out, gamma, beta);
}